// Round 1
// baseline (492.348 us; speedup 1.0000x reference)
//
#include <hip/hip_runtime.h>
#include <hip/hip_bf16.h>

// ---------------------------------------------------------------------------
// EdgeNetwork: out[e] = tanh(relu(cat(h[dst[e]], h[src[e]], dR[e]) @ W1 + b1) @ W2 + b2)
// E=640000, F=128, MID=192, OUT=128.  bf16 MFMA (16x16x32), fp32 accumulate.
// ---------------------------------------------------------------------------

#define F_IN   128
#define MID    192
#define OUT_N  128
#define K1     256          // 2*F (dR column handled as rank-1 epilogue)
#define M_TILE 64           // edges per block
#define A_STRIDE 264        // bf16 elements; 264*2=528 B -> 132 dwords == 4 mod 32 banks
#define H_STRIDE 200        // bf16 elements; 400 B -> 100 dwords == 4 mod 32 banks

typedef __attribute__((ext_vector_type(8))) short bf16x8;   // 8 bf16 = 4 VGPRs
typedef __attribute__((ext_vector_type(4))) float f32x4;

__device__ __forceinline__ unsigned short f2bf(float f) {
    unsigned u = __builtin_bit_cast(unsigned, f);
    u = (u + 0x7FFFu + ((u >> 16) & 1u)) >> 16;   // round-to-nearest-even
    return (unsigned short)u;
}

// Pack W1 (rows 0..255) and W2 into bf16, B-fragment-major:
//   p[(ktile*N + n)*32 + kin], k = ktile*32 + kin.
// Also copy W1 row 256 (dR weights) as fp32.
__global__ void pack_weights(const float* __restrict__ W1,
                             const float* __restrict__ W2,
                             unsigned short* __restrict__ p1,
                             unsigned short* __restrict__ p2,
                             float* __restrict__ wdr) {
    int i = blockIdx.x * 256 + threadIdx.x;
    if (i < K1 * MID) {              // 49152
        int kin = i & 31;
        int rest = i >> 5;
        int n = rest % MID;
        int kt = rest / MID;
        p1[i] = f2bf(W1[(kt * 32 + kin) * MID + n]);
    }
    int j = i - K1 * MID;
    if (j >= 0 && j < MID * OUT_N) { // 24576
        int kin = j & 31;
        int rest = j >> 5;
        int n = rest & 127;
        int kt = rest >> 7;
        p2[j] = f2bf(W2[(kt * 32 + kin) * OUT_N + n]);
    }
    if (i < MID) wdr[i] = W1[256 * MID + i];
}

__global__ __launch_bounds__(256, 4)
void edge_mlp_kernel(const float* __restrict__ h,
                     const float* __restrict__ dR,
                     const int*   __restrict__ src_idx,
                     const int*   __restrict__ dst_idx,
                     const float* __restrict__ b1,
                     const float* __restrict__ b2,
                     const unsigned short* __restrict__ p1,
                     const unsigned short* __restrict__ p2,
                     const float* __restrict__ wdr,
                     float* __restrict__ out) {
    __shared__ __align__(16) unsigned short sA[M_TILE * A_STRIDE]; // 33792 B (hid aliases)
    __shared__ float sdr[M_TILE];

    const int tid = threadIdx.x;
    const int e0 = blockIdx.x * M_TILE;

    if (tid < M_TILE) sdr[tid] = dR[e0 + tid];

    // ---- stage A tile: A[e][0:128]=h[dst[e]], A[e][128:256]=h[src[e]] (bf16) ----
    {
        const int j = tid & 31;      // float4 slot within a 128-float row
        const int g = tid >> 5;      // 0..7: which row-half this group does
#pragma unroll
        for (int it = 0; it < 16; ++it) {
            int half = it * 8 + g;           // 0..127
            int e = half >> 1;
            int part = half & 1;             // 0=dst, 1=src
            const int* ip = part ? src_idx : dst_idx;
            int row = ip[e0 + e];
            const float4 v = *(const float4*)(h + (size_t)row * F_IN + j * 4);
            ushort4 b;
            b.x = f2bf(v.x); b.y = f2bf(v.y); b.z = f2bf(v.z); b.w = f2bf(v.w);
            *(ushort4*)(&sA[e * A_STRIDE + part * F_IN + j * 4]) = b;
        }
    }
    __syncthreads();

    const int lane = tid & 63;
    const int w = tid >> 6;          // wave 0..3
    const int l15 = lane & 15;
    const int q = lane >> 4;

    // ---- layer 1: hid[64][192] = relu(A @ W1 + b1 + dR*wdr) ----
    // wave w owns n-tiles {w, w+4, w+8}; m-subtiles 0..3
    f32x4 acc1[4][3] = {};
    for (int kt = 0; kt < 8; ++kt) {
        bf16x8 a[4];
#pragma unroll
        for (int m = 0; m < 4; ++m)
            a[m] = *(const bf16x8*)(&sA[(m * 16 + l15) * A_STRIDE + kt * 32 + q * 8]);
#pragma unroll
        for (int ni = 0; ni < 3; ++ni) {
            int nb = (w + ni * 4) * 16 + l15;
            bf16x8 bf = *(const bf16x8*)(&p1[(kt * MID + nb) * 32 + q * 8]);
#pragma unroll
            for (int m = 0; m < 4; ++m)
                acc1[m][ni] = __builtin_amdgcn_mfma_f32_16x16x32_bf16(a[m], bf, acc1[m][ni], 0, 0, 0);
        }
    }
    __syncthreads();   // everyone done reading sA before hid overwrites it

    // ---- epilogue 1 -> hid (bf16) in LDS, aliasing sA ----
    unsigned short* sH = sA;
#pragma unroll
    for (int ni = 0; ni < 3; ++ni) {
        int n = (w + ni * 4) * 16 + l15;
        float bb = b1[n];
        float wd = wdr[n];
#pragma unroll
        for (int m = 0; m < 4; ++m) {
#pragma unroll
            for (int r = 0; r < 4; ++r) {
                int e = m * 16 + q * 4 + r;
                float v = acc1[m][ni][r] + bb + sdr[e] * wd;
                v = fmaxf(v, 0.0f);
                sH[e * H_STRIDE + n] = f2bf(v);
            }
        }
    }
    __syncthreads();

    // ---- layer 2: out = tanh(hid @ W2 + b2); wave w owns n-tiles {w, w+4} ----
    f32x4 acc2[4][2] = {};
    for (int kt = 0; kt < 6; ++kt) {
        bf16x8 a[4];
#pragma unroll
        for (int m = 0; m < 4; ++m)
            a[m] = *(const bf16x8*)(&sH[(m * 16 + l15) * H_STRIDE + kt * 32 + q * 8]);
#pragma unroll
        for (int ni = 0; ni < 2; ++ni) {
            int nb = (w + ni * 4) * 16 + l15;
            bf16x8 bf = *(const bf16x8*)(&p2[(kt * OUT_N + nb) * 32 + q * 8]);
#pragma unroll
            for (int m = 0; m < 4; ++m)
                acc2[m][ni] = __builtin_amdgcn_mfma_f32_16x16x32_bf16(a[m], bf, acc2[m][ni], 0, 0, 0);
        }
    }

    // ---- epilogue 2: tanh + store fp32 ----
#pragma unroll
    for (int ni = 0; ni < 2; ++ni) {
        int n = (w + ni * 4) * 16 + l15;
        float bb = b2[n];
#pragma unroll
        for (int m = 0; m < 4; ++m) {
#pragma unroll
            for (int r = 0; r < 4; ++r) {
                int e = e0 + m * 16 + q * 4 + r;
                float x = acc2[m][ni][r] + bb;
                x = fminf(fmaxf(x, -10.0f), 10.0f);
                float t = __expf(2.0f * x);               // tanh = (e^2x - 1)/(e^2x + 1)
                out[(size_t)e * OUT_N + n] = (t - 1.0f) * __builtin_amdgcn_rcpf(t + 1.0f);
            }
        }
    }
}

extern "C" void kernel_launch(void* const* d_in, const int* in_sizes, int n_in,
                              void* d_out, int out_size, void* d_ws, size_t ws_size,
                              hipStream_t stream) {
    const float* h   = (const float*)d_in[0];
    const float* dR  = (const float*)d_in[1];
    const int* src   = (const int*)d_in[2];
    const int* dst   = (const int*)d_in[3];
    const float* W1  = (const float*)d_in[4];
    const float* b1  = (const float*)d_in[5];
    const float* W2  = (const float*)d_in[6];
    const float* b2  = (const float*)d_in[7];
    float* out       = (float*)d_out;

    unsigned short* p1 = (unsigned short*)d_ws;            // 49152 bf16 = 98304 B
    unsigned short* p2 = p1 + K1 * MID;                    // 24576 bf16 = 49152 B
    float* wdr         = (float*)(p2 + MID * OUT_N);       // 192 fp32

    const int E = in_sizes[1];

    pack_weights<<<(K1 * MID + MID * OUT_N + 255) / 256, 256, 0, stream>>>(W1, W2, p1, p2, wdr);
    edge_mlp_kernel<<<E / M_TILE, 256, 0, stream>>>(h, dR, src, dst, b1, b2, p1, p2, wdr, out);
}